// Round 2
// baseline (1461.253 us; speedup 1.0000x reference)
//
#include <hip/hip_runtime.h>

#define NS   16384
#define NF1c 2000
#define NF2c 10000
#define NH   512
#define KC   19
#define NREC 12000

typedef short bf16x8 __attribute__((ext_vector_type(8)));
typedef float f32x4  __attribute__((ext_vector_type(4)));

__device__ __forceinline__ unsigned short f2bf(float x) {
    unsigned int u = __builtin_bit_cast(unsigned int, x);
    u += 0x7FFFu + ((u >> 16) & 1u);          // round-to-nearest-even
    return (unsigned short)(u >> 16);
}
__device__ __forceinline__ float bf2f(unsigned short h) {
    return __builtin_bit_cast(float, (unsigned int)h << 16);
}

// ---------------- prep kernels ----------------
__global__ void k_cvt(const float* __restrict__ s, unsigned short* __restrict__ d, int n4) {
    int i = blockIdx.x * blockDim.x + threadIdx.x;
    int st = gridDim.x * blockDim.x;
    for (; i < n4; i += st) {
        float4 f = ((const float4*)s)[i];
        ushort4 o;
        o.x = f2bf(f.x); o.y = f2bf(f.y); o.z = f2bf(f.z); o.w = f2bf(f.w);
        ((ushort4*)d)[i] = o;
    }
}

__global__ void k_prep_st(const float* __restrict__ g, const float* __restrict__ be,
                          const float* __restrict__ m, const float* __restrict__ v,
                          const float* __restrict__ b1,
                          float* __restrict__ s, float* __restrict__ t, int n) {
    int i = blockIdx.x * blockDim.x + threadIdx.x;
    if (i < n) {
        float sc = g[i] * rsqrtf(v[i] + 1e-5f);
        s[i] = sc;
        t[i] = be[i] + (b1[i] - m[i]) * sc;
    }
}

__global__ void k_zero(float* __restrict__ p, int n) {
    int i = blockIdx.x * blockDim.x + threadIdx.x;
    if (i < n) p[i] = 0.f;
}

// ---------------- GEMM: C[M,Nn] = A[M,K] * B[Nn,K]^T  (both row-major, K fast) ----------
// Software-pipelined: double-buffered LDS, one barrier per K-step, loads for
// tile t+1 issued during tile t's compute (vmcnt wait deferred to next ds_write).
// EPI 0: h = bf16(relu(acc*sc[col]+sh[col])) -> Hout (ld = NH)
// EPI 1: Fout[row*Nn+col] = acc + sc[col]  (col guarded)
// A_BF16 0: A fp32 (convert at ds_write); 1: A bf16 (K must be a multiple of 32)
template<int EPI, int A_BF16>
__global__ __launch_bounds__(256)
void k_gemm(const void* __restrict__ Aptr, const unsigned short* __restrict__ B,
            int K, int Nn, int ntn,
            const float* __restrict__ sc, const float* __restrict__ sh,
            unsigned short* __restrict__ Hout, float* __restrict__ Fout)
{
    __shared__ __align__(16) unsigned short As[2][128 * 32];
    __shared__ __align__(16) unsigned short Bs[2][128 * 32];
    // bijective XCD swizzle: XCD x owns logical ids [x*q, (x+1)*q) -> same-tm
    // blocks (which share the A panel) co-reside on one XCD's L2.
    const int nwg = gridDim.x;            // launcher guarantees nwg % 8 == 0
    const int q8  = nwg >> 3;
    const int L   = (blockIdx.x & 7) * q8 + (blockIdx.x >> 3);
    const int tn  = L % ntn, tm = L / ntn;

    const int tid  = threadIdx.x;
    const int wave = tid >> 6, lane = tid & 63;
    const int wr   = wave >> 1, wc = wave & 1;
    const int lo   = lane & 15, hi = lane >> 4;
    const int srow = tid >> 1, shalf = tid & 1;
    const long arow = (long)tm * 128 + srow;
    const int  brow = tn * 128 + srow;

    f32x4 acc[4][4];
#pragma unroll
    for (int i = 0; i < 4; i++)
#pragma unroll
        for (int j = 0; j < 4; j++) acc[i][j] = (f32x4){0.f, 0.f, 0.f, 0.f};

    // swizzled chunk byte offset inside a [128 rows][4 chunks of 16B] tile
    const int wc0 = (srow << 6) + ((((shalf * 2)    ) ^ ((srow >> 1) & 3)) << 4);
    const int wc1 = (srow << 6) + ((((shalf * 2) + 1) ^ ((srow >> 1) & 3)) << 4);

    // raw staging registers (unconverted; convert at ds_write time so the
    // vmcnt wait lands one iteration after issue)
    float4 rfa[4];                 // A fp32 raw
    uint4  ra0, ra1;               // A bf16 raw
    uint4  rb0, rb1;               // B raw

    auto issue_load = [&](int k0) {
        const int kb = k0 + shalf * 16;
        if (A_BF16) {
            const unsigned short* ap = (const unsigned short*)Aptr + arow * (long)K + kb;
            ra0 = *(const uint4*)ap;
            ra1 = *(const uint4*)(ap + 8);
        } else {
            const float* ap = (const float*)Aptr + arow * (long)K + kb;
            if (kb + 16 <= K) {
                rfa[0] = ((const float4*)ap)[0];
                rfa[1] = ((const float4*)ap)[1];
                rfa[2] = ((const float4*)ap)[2];
                rfa[3] = ((const float4*)ap)[3];
            } else {
#pragma unroll
                for (int j = 0; j < 16; j++)
                    ((float*)rfa)[j] = (kb + j < K) ? ap[j] : 0.f;
            }
        }
        rb0 = (uint4){0, 0, 0, 0}; rb1 = (uint4){0, 0, 0, 0};
        if (brow < Nn && kb < K) {
            const unsigned short* bp = B + (long)brow * K + kb;
            if (kb + 16 <= K) {
                rb0 = *(const uint4*)bp;
                rb1 = *(const uint4*)(bp + 8);
            } else {
                __align__(16) unsigned short tb[16];
#pragma unroll
                for (int j = 0; j < 16; j++)
                    tb[j] = (kb + j < K) ? bp[j] : (unsigned short)0;
                rb0 = *(uint4*)&tb[0]; rb1 = *(uint4*)&tb[8];
            }
        }
    };

    auto write_lds = [&](int buf) {
        char* Ab = (char*)As[buf];
        char* Bb = (char*)Bs[buf];
        __align__(16) unsigned short u[16];
        if (A_BF16) {
            *(uint4*)&u[0] = ra0; *(uint4*)&u[8] = ra1;
        } else {
#pragma unroll
            for (int j = 0; j < 16; j++) u[j] = f2bf(((const float*)rfa)[j]);
        }
        *(uint4*)(Ab + wc0) = *(uint4*)&u[0];
        *(uint4*)(Ab + wc1) = *(uint4*)&u[8];
        *(uint4*)(Bb + wc0) = rb0;
        *(uint4*)(Bb + wc1) = rb1;
    };

    auto compute = [&](int buf) {
        char* Ab = (char*)As[buf];
        char* Bb = (char*)Bs[buf];
        bf16x8 af[4], bfr[4];
#pragma unroll
        for (int f = 0; f < 4; f++) {
            int ar = wr * 64 + f * 16 + lo;
            af[f]  = *(const bf16x8*)(Ab + (ar << 6) + ((hi ^ ((ar >> 1) & 3)) << 4));
            int br = wc * 64 + f * 16 + lo;
            bfr[f] = *(const bf16x8*)(Bb + (br << 6) + ((hi ^ ((br >> 1) & 3)) << 4));
        }
#pragma unroll
        for (int i = 0; i < 4; i++)
#pragma unroll
            for (int j = 0; j < 4; j++)
                acc[i][j] = __builtin_amdgcn_mfma_f32_16x16x32_bf16(af[i], bfr[j], acc[i][j], 0, 0, 0);
    };

    const int nt = (K + 31) / 32;
    issue_load(0);
    for (int t = 0; t < nt; ++t) {
        write_lds(t & 1);                     // waits vmcnt for loads issued @ t-1
        if (t + 1 < nt) issue_load((t + 1) * 32);
        __syncthreads();
        compute(t & 1);
    }

    // ---- epilogue  (C/D layout: col = lane&15, row = (lane>>4)*4 + reg)
#pragma unroll
    for (int i = 0; i < 4; i++) {
#pragma unroll
        for (int j = 0; j < 4; j++) {
            const int col = tn * 128 + wc * 64 + j * 16 + lo;
#pragma unroll
            for (int r = 0; r < 4; r++) {
                const long row = (long)tm * 128 + wr * 64 + i * 16 + hi * 4 + r;
                float v = acc[i][j][r];
                if (EPI == 0) {
                    v = fmaxf(v * sc[col] + sh[col], 0.f);
                    Hout[row * NH + col] = f2bf(v);
                } else {
                    if (col < Nn) Fout[row * (long)Nn + col] = v + sc[col];
                }
            }
        }
    }
}

// ---------------- stage C: projections + scatter ----------------
__global__ __launch_bounds__(256)
void k_proj(const unsigned short* __restrict__ h_rna,
            const unsigned short* __restrict__ h_atac,
            const float* __restrict__ W_rmu, const float* __restrict__ b_rmu,
            const float* __restrict__ W_rvar, const float* __restrict__ b_rvar,
            const float* __restrict__ W_amu, const float* __restrict__ b_amu,
            const float* __restrict__ W_avar, const float* __restrict__ b_avar,
            const int* __restrict__ idx_rna, const int* __restrict__ idx_atac,
            float* __restrict__ mu0, float* __restrict__ var0,
            float* __restrict__ mu1, float* __restrict__ var1,
            float* __restrict__ mflag)
{
    __shared__ __align__(16) unsigned short hsh[4][2][NH];
    const int wave = threadIdx.x >> 6, lane = threadIdx.x & 63;
    const long i = (long)blockIdx.x * 4 + wave;
    *(uint4*)&hsh[wave][0][lane * 8] = *(const uint4*)(h_rna  + i * NH + lane * 8);
    *(uint4*)&hsh[wave][1][lane * 8] = *(const uint4*)(h_atac + i * NH + lane * 8);
    __syncthreads();
    const int mod = lane >> 5, oo = lane & 31;
    const int isv = oo >> 4, o = oo & 15;
    const float *W, *bias;
    if (mod == 0) { W = isv ? W_rvar : W_rmu; bias = isv ? b_rvar : b_rmu; }
    else          { W = isv ? W_avar : W_amu; bias = isv ? b_avar : b_amu; }
    const unsigned short* hr = hsh[wave][mod];
    const float* wrow = W + o * NH;
    float a = 0.f;
#pragma unroll 4
    for (int k = 0; k < NH; k += 4) {
        float4 w = *(const float4*)(wrow + k);
        a += bf2f(hr[k]) * w.x + bf2f(hr[k+1]) * w.y + bf2f(hr[k+2]) * w.z + bf2f(hr[k+3]) * w.w;
    }
    a += bias[o];
    const int tgt = (mod == 0) ? idx_rna[i] : idx_atac[i];
    float* mu  = mod ? mu1  : mu0;
    float* var = mod ? var1 : var0;
    if (!isv) mu[(long)tgt * 16 + o] = a;
    else      var[(long)tgt * 16 + o] = expf(a);
    if (oo == 0) mflag[(long)mod * NS + tgt] = 1.f;
}

// ---------------- stage C: PoE combine + q + decoder hidden ----------------
__global__ __launch_bounds__(256)
void k_combine(const float* __restrict__ mu0, const float* __restrict__ var0,
               const float* __restrict__ mu1, const float* __restrict__ var1,
               const float* __restrict__ mflag,
               const float* __restrict__ eps, const float* __restrict__ cluster,
               const float* __restrict__ W_d1,
               const float* __restrict__ s_d, const float* __restrict__ t_d,
               float* __restrict__ o_zmu, float* __restrict__ o_zvar,
               float* __restrict__ o_z, float* __restrict__ o_q,
               unsigned short* __restrict__ h_d)
{
    __shared__ float zsh[4][16];
    const int wave = threadIdx.x >> 6, lane = threadIdx.x & 63;
    const long i = (long)blockIdx.x * 4 + wave;
    if (lane < 16) {
        const int d = lane;
        const float f0 = mflag[i], f1 = mflag[NS + i];
        float ts = 1.f, num = 0.f;
        if (f0 != 0.f) { float iv = 1.f / var0[i*16+d]; ts += iv; num += mu0[i*16+d] * iv; }
        if (f1 != 0.f) { float iv = 1.f / var1[i*16+d]; ts += iv; num += mu1[i*16+d] * iv; }
        const float zm = num / ts, zv = 1.f / ts;
        const float z = zm + zv * eps[i*16+d];
        o_zmu[i*16+d] = zm; o_zvar[i*16+d] = zv; o_z[i*16+d] = z;
        zsh[wave][d] = z;
    }
    __syncthreads();
    float zreg[16];
#pragma unroll
    for (int d = 0; d < 16; d++) zreg[d] = zsh[wave][d];
    float qk = 0.f;
    if (lane < KC) {
        float d2 = 0.f;
#pragma unroll
        for (int d = 0; d < 16; d++) { float df = zreg[d] - cluster[lane*16+d]; d2 += df*df; }
        qk = 1.f / (1.f + d2);
    }
    float ssum = qk;
#pragma unroll
    for (int off = 16; off > 0; off >>= 1) ssum += __shfl_xor(ssum, off, 32);
    if (lane < KC) o_q[i * KC + lane] = qk / ssum;
#pragma unroll
    for (int j = 0; j < 8; j++) {
        const int c = lane + 64 * j;
        float a = 0.f;
#pragma unroll
        for (int d = 0; d < 16; d += 4) {
            float4 w = *(const float4*)(W_d1 + c * 16 + d);
            a += zreg[d] * w.x + zreg[d+1] * w.y + zreg[d+2] * w.z + zreg[d+3] * w.w;
        }
        a = fmaxf(a * s_d[c] + t_d[c], 0.f);
        h_d[i * NH + c] = f2bf(a);
    }
}

// ---------------- launcher ----------------
extern "C" void kernel_launch(void* const* d_in, const int* in_sizes, int n_in,
                              void* d_out, int out_size, void* d_ws, size_t ws_size,
                              hipStream_t stream)
{
    const float* rna    = (const float*)d_in[0];
    const float* atac   = (const float*)d_in[1];
    const int*   i_rna  = (const int*)d_in[2];
    const int*   i_atac = (const int*)d_in[3];
    const float* eps    = (const float*)d_in[4];
    const float* W_r1   = (const float*)d_in[5];
    const float* b_r1   = (const float*)d_in[6];
    const float* g_r    = (const float*)d_in[7];
    const float* be_r   = (const float*)d_in[8];
    const float* m_r    = (const float*)d_in[9];
    const float* v_r    = (const float*)d_in[10];
    const float* W_rmu  = (const float*)d_in[11];
    const float* b_rmu  = (const float*)d_in[12];
    const float* W_rvar = (const float*)d_in[13];
    const float* b_rvar = (const float*)d_in[14];
    const float* W_a1   = (const float*)d_in[15];
    const float* b_a1   = (const float*)d_in[16];
    const float* g_a    = (const float*)d_in[17];
    const float* be_a   = (const float*)d_in[18];
    const float* m_a    = (const float*)d_in[19];
    const float* v_a    = (const float*)d_in[20];
    const float* W_amu  = (const float*)d_in[21];
    const float* b_amu  = (const float*)d_in[22];
    const float* W_avar = (const float*)d_in[23];
    const float* b_avar = (const float*)d_in[24];
    const float* W_d1   = (const float*)d_in[25];
    const float* b_d1   = (const float*)d_in[26];
    const float* g_d    = (const float*)d_in[27];
    const float* be_d   = (const float*)d_in[28];
    const float* m_d    = (const float*)d_in[29];
    const float* v_d    = (const float*)d_in[30];
    const float* W_d4   = (const float*)d_in[31];
    const float* b_d4   = (const float*)d_in[32];
    const float* clus   = (const float*)d_in[33];
    (void)in_sizes; (void)n_in; (void)out_size;

    char* w = (char*)d_ws;
    size_t off = 0;
    auto carve = [&](size_t bytes) { void* p = w + off; off += (bytes + 255) & ~(size_t)255; return p; };
    unsigned short* wr1b  = (unsigned short*)carve((size_t)NH * NF1c * 2);
    unsigned short* wa1b  = (unsigned short*)carve((size_t)NH * NF2c * 2);
    unsigned short* wd4b  = (unsigned short*)carve((size_t)NREC * NH * 2);
    unsigned short* hrna  = (unsigned short*)carve((size_t)NS * NH * 2);
    unsigned short* hatac = (unsigned short*)carve((size_t)NS * NH * 2);
    unsigned short* hd    = (unsigned short*)carve((size_t)NS * NH * 2);
    float* mu0   = (float*)carve((size_t)NS * 16 * 4);
    float* var0  = (float*)carve((size_t)NS * 16 * 4);
    float* mu1   = (float*)carve((size_t)NS * 16 * 4);
    float* var1  = (float*)carve((size_t)NS * 16 * 4);
    float* mflag = (float*)carve((size_t)2 * NS * 4);
    float* st    = (float*)carve((size_t)6 * NH * 4);
    if (off > ws_size) return;  // insufficient workspace -> loud validation failure

    float* s_r = st;          float* t_r = st + NH;
    float* s_a = st + 2*NH;   float* t_a = st + 3*NH;
    float* s_d = st + 4*NH;   float* t_d = st + 5*NH;

    float* out    = (float*)d_out;
    float* o_rec  = out;
    float* o_zmu  = out + (size_t)NS * NREC;
    float* o_zvar = o_zmu + (size_t)NS * 16;
    float* o_z    = o_zvar + (size_t)NS * 16;
    float* o_q    = o_z + (size_t)NS * 16;

    // prep
    k_cvt<<<1024, 256, 0, stream>>>(W_r1, wr1b, NH * NF1c / 4);
    k_cvt<<<2048, 256, 0, stream>>>(W_a1, wa1b, NH * NF2c / 4);
    k_cvt<<<2048, 256, 0, stream>>>(W_d4, wd4b, NREC * NH / 4);
    k_prep_st<<<2, 256, 0, stream>>>(g_r, be_r, m_r, v_r, b_r1, s_r, t_r, NH);
    k_prep_st<<<2, 256, 0, stream>>>(g_a, be_a, m_a, v_a, b_a1, s_a, t_a, NH);
    k_prep_st<<<2, 256, 0, stream>>>(g_d, be_d, m_d, v_d, b_d1, s_d, t_d, NH);
    k_zero<<<(2 * NS + 255) / 256, 256, 0, stream>>>(mflag, 2 * NS);

    dim3 blk(256);
    // encoder GEMMs: ntn=4 (N=512), ntm=128 -> 512 blocks (512 % 8 == 0)
    k_gemm<0, 0><<<512, blk, 0, stream>>>(rna,  wr1b, NF1c, NH, 4, s_r, t_r, hrna,  nullptr);
    k_gemm<0, 0><<<512, blk, 0, stream>>>(atac, wa1b, NF2c, NH, 4, s_a, t_a, hatac, nullptr);
    k_proj<<<NS / 4, blk, 0, stream>>>(hrna, hatac, W_rmu, b_rmu, W_rvar, b_rvar,
                                       W_amu, b_amu, W_avar, b_avar, i_rna, i_atac,
                                       mu0, var0, mu1, var1, mflag);
    k_combine<<<NS / 4, blk, 0, stream>>>(mu0, var0, mu1, var1, mflag, eps, clus,
                                          W_d1, s_d, t_d, o_zmu, o_zvar, o_z, o_q, hd);
    // recon GEMM: ntn=94 (N=12000), ntm=128 -> 12032 blocks (12032 % 8 == 0)
    k_gemm<1, 1><<<94 * 128, blk, 0, stream>>>(hd, wd4b, NH, NREC, 94, b_d4, nullptr, nullptr, o_rec);
}

// Round 4
// 1226.678 us; speedup vs baseline: 1.1912x; 1.1912x over previous
//
#include <hip/hip_runtime.h>

#define NS   16384
#define NF1c 2000
#define NF2c 10000
#define NH   512
#define KC   19
#define NREC 12000

typedef short bf16x8 __attribute__((ext_vector_type(8)));
typedef float f32x4  __attribute__((ext_vector_type(4)));

__device__ __forceinline__ unsigned short f2bf(float x) {
    unsigned int u = __builtin_bit_cast(unsigned int, x);
    u += 0x7FFFu + ((u >> 16) & 1u);          // round-to-nearest-even
    return (unsigned short)(u >> 16);
}
__device__ __forceinline__ float bf2f(unsigned short h) {
    return __builtin_bit_cast(float, (unsigned int)h << 16);
}

// raw barrier WITHOUT the __syncthreads vmcnt drain: LDS ops flushed, but
// prefetch global loads stay in flight across the barrier (T4).
__device__ __forceinline__ void sync_nodrain() {
    asm volatile("s_waitcnt lgkmcnt(0)" ::: "memory");
    __builtin_amdgcn_s_barrier();
    asm volatile("" ::: "memory");
}

// ---------------- prep kernels ----------------
__global__ void k_cvt(const float* __restrict__ s, unsigned short* __restrict__ d, int n4) {
    int i = blockIdx.x * blockDim.x + threadIdx.x;
    int st = gridDim.x * blockDim.x;
    for (; i < n4; i += st) {
        float4 f = ((const float4*)s)[i];
        ushort4 o;
        o.x = f2bf(f.x); o.y = f2bf(f.y); o.z = f2bf(f.z); o.w = f2bf(f.w);
        ((ushort4*)d)[i] = o;
    }
}

__global__ void k_prep_st(const float* __restrict__ g, const float* __restrict__ be,
                          const float* __restrict__ m, const float* __restrict__ v,
                          const float* __restrict__ b1,
                          float* __restrict__ s, float* __restrict__ t, int n) {
    int i = blockIdx.x * blockDim.x + threadIdx.x;
    if (i < n) {
        float sc = g[i] * rsqrtf(v[i] + 1e-5f);
        s[i] = sc;
        t[i] = be[i] + (b1[i] - m[i]) * sc;
    }
}

__global__ void k_zero(float* __restrict__ p, int n) {
    int i = blockIdx.x * blockDim.x + threadIdx.x;
    if (i < n) p[i] = 0.f;
}

// LDS chunk swizzle. BK=32: row stride 64B -> rows alternate half-banks,
// chunk ^= (r>>1)&3 (0 conflicts measured). BK=64: row stride 128B -> all
// rows bank-aligned, chunk ^= r&7 spreads the 8 chunk-bank-groups evenly.
template<int BK> __device__ __forceinline__ int swz(int r) {
    return (BK == 32) ? ((r >> 1) & 3) : (r & 7);
}

// ---------------- GEMM: C[M,Nn] = A[M,K] * B[Nn,K]^T  (both row-major, K fast) ----------
// Pipelined: dbuf LDS, ONE raw barrier per K-step (no vmcnt drain), loads for
// tile t+1 issued during tile t, consumed (vmcnt-waited) at t+1's ds_write.
// EPI 0: h = bf16(relu(acc*sc[col]+sh[col])) -> Hout (ld = NH)
// EPI 1: Fout[row*Nn+col] = acc + sc[col]  (col guarded)
// A_BF16 0: A fp32 (convert at ds_write); 1: A bf16
template<int EPI, int A_BF16, int BK>
__global__ __launch_bounds__(256)
void k_gemm(const void* __restrict__ Aptr, const unsigned short* __restrict__ B,
            int K, int Nn, int ntn,
            const float* __restrict__ sc, const float* __restrict__ sh,
            unsigned short* __restrict__ Hout, float* __restrict__ Fout)
{
    constexpr int CH = BK / 8;    // 16B chunks per row (BK bf16 elems = BK*2 bytes)
    constexpr int JC = CH / 2;    // chunks staged per thread (2 threads/row)
    __shared__ __align__(16) unsigned short As[2][128 * BK];
    __shared__ __align__(16) unsigned short Bs[2][128 * BK];

    // bijective XCD swizzle: same-tm blocks (sharing the A panel) co-reside
    const int nwg = gridDim.x;            // launcher guarantees nwg % 8 == 0
    const int q8  = nwg >> 3;
    const int L   = (blockIdx.x & 7) * q8 + (blockIdx.x >> 3);
    const int tn  = L % ntn, tm = L / ntn;

    const int tid  = threadIdx.x;
    const int wave = tid >> 6, lane = tid & 63;
    const int wr   = wave >> 1, wc = wave & 1;
    const int lo   = lane & 15, hi = lane >> 4;
    const int srow = tid >> 1, shalf = tid & 1;
    const long arow = (long)tm * 128 + srow;
    const int  brow = tn * 128 + srow;
    const bool bok  = (brow < Nn);

    const float*          Af  = (const float*)Aptr + arow * (long)K;
    const unsigned short* A16 = (const unsigned short*)Aptr + arow * (long)K;
    const unsigned short* Bp  = B + (long)brow * K;

    f32x4 acc[4][4];
#pragma unroll
    for (int i = 0; i < 4; i++)
#pragma unroll
        for (int j = 0; j < 4; j++) acc[i][j] = (f32x4){0.f, 0.f, 0.f, 0.f};

    float4 rfa[BK / 8];           // A raw fp32 (A_BF16=0): BK/2 floats
    uint4  ra[JC];                // A raw bf16 (A_BF16=1)
    uint4  rb[JC];                // B raw bf16

    auto issue_load = [&](int k0, bool tail) {
        const int kb = k0 + shalf * (BK / 2);
        if (A_BF16) {
            if (!tail) {
#pragma unroll
                for (int j = 0; j < JC; j++) ra[j] = *(const uint4*)(A16 + kb + j * 8);
            } else {
#pragma unroll
                for (int j = 0; j < JC; j++) {
                    __align__(16) unsigned short t8[8];
#pragma unroll
                    for (int e = 0; e < 8; e++)
                        t8[e] = (kb + j * 8 + e < K) ? A16[kb + j * 8 + e] : (unsigned short)0;
                    ra[j] = *(uint4*)t8;
                }
            }
        } else {
            if (!tail) {
#pragma unroll
                for (int q = 0; q < BK / 8; q++) rfa[q] = *(const float4*)(Af + kb + q * 4);
            } else {
#pragma unroll
                for (int q = 0; q < BK / 8; q++) {
                    float4 f;
                    f.x = (kb + q * 4 + 0 < K) ? Af[kb + q * 4 + 0] : 0.f;
                    f.y = (kb + q * 4 + 1 < K) ? Af[kb + q * 4 + 1] : 0.f;
                    f.z = (kb + q * 4 + 2 < K) ? Af[kb + q * 4 + 2] : 0.f;
                    f.w = (kb + q * 4 + 3 < K) ? Af[kb + q * 4 + 3] : 0.f;
                    rfa[q] = f;
                }
            }
        }
#pragma unroll
        for (int j = 0; j < JC; j++) rb[j] = (uint4){0, 0, 0, 0};
        if (bok) {
            if (!tail) {
#pragma unroll
                for (int j = 0; j < JC; j++) rb[j] = *(const uint4*)(Bp + kb + j * 8);
            } else {
#pragma unroll
                for (int j = 0; j < JC; j++) {
                    __align__(16) unsigned short t8[8];
#pragma unroll
                    for (int e = 0; e < 8; e++)
                        t8[e] = (kb + j * 8 + e < K) ? Bp[kb + j * 8 + e] : (unsigned short)0;
                    rb[j] = *(uint4*)t8;
                }
            }
        }
    };

    auto write_lds = [&](int buf) {
        char* Ap = (char*)As[buf];
        char* Bq = (char*)Bs[buf];
        const int rbase = srow * (2 * BK);
        const int sw = swz<BK>(srow);
#pragma unroll
        for (int j = 0; j < JC; j++) {
            const int c = shalf * JC + j;
            const int pos = rbase + ((c ^ sw) << 4);
            uint4 av;
            if (A_BF16) {
                av = ra[j];
            } else {
                __align__(16) unsigned short u8[8];
#pragma unroll
                for (int e = 0; e < 8; e++) u8[e] = f2bf(((const float*)&rfa[2 * j])[e]);
                av = *(uint4*)u8;
            }
            *(uint4*)(Ap + pos) = av;
            *(uint4*)(Bq + pos) = rb[j];
        }
    };

    auto compute = [&](int buf) {
        const char* Ap = (const char*)As[buf];
        const char* Bq = (const char*)Bs[buf];
#pragma unroll
        for (int s = 0; s < BK / 32; s++) {
            bf16x8 af[4], bfv[4];
#pragma unroll
            for (int f = 0; f < 4; f++) {
                const int ar = wr * 64 + f * 16 + lo;
                af[f]  = *(const bf16x8*)(Ap + ar * (2 * BK) + (((s * 4 + hi) ^ swz<BK>(ar)) << 4));
                const int br = wc * 64 + f * 16 + lo;
                bfv[f] = *(const bf16x8*)(Bq + br * (2 * BK) + (((s * 4 + hi) ^ swz<BK>(br)) << 4));
            }
#pragma unroll
            for (int i = 0; i < 4; i++)
#pragma unroll
                for (int j = 0; j < 4; j++)
                    acc[i][j] = __builtin_amdgcn_mfma_f32_16x16x32_bf16(af[i], bfv[j], acc[i][j], 0, 0, 0);
        }
    };

    const int ntf = K / BK;
    const bool has_rem = (K % BK) != 0;
    const int nt = ntf + (has_rem ? 1 : 0);
    issue_load(0, has_rem && nt == 1);
    for (int t = 0; t < nt; ++t) {
        write_lds(t & 1);                       // vmcnt wait for loads issued @ t-1
        if (t + 1 < nt) issue_load((t + 1) * BK, has_rem && (t + 1 == nt - 1));
        sync_nodrain();                         // lgkm-only wait + raw s_barrier
        compute(t & 1);
    }

    // ---- epilogue  (C/D layout: col = lane&15, row = (lane>>4)*4 + reg)
#pragma unroll
    for (int i = 0; i < 4; i++) {
#pragma unroll
        for (int j = 0; j < 4; j++) {
            const int col = tn * 128 + wc * 64 + j * 16 + lo;
#pragma unroll
            for (int r = 0; r < 4; r++) {
                const long row = (long)tm * 128 + wr * 64 + i * 16 + hi * 4 + r;
                float v = acc[i][j][r];
                if (EPI == 0) {
                    v = fmaxf(v * sc[col] + sh[col], 0.f);
                    Hout[row * NH + col] = f2bf(v);
                } else {
                    if (col < Nn) Fout[row * (long)Nn + col] = v + sc[col];
                }
            }
        }
    }
}

// ---------------- stage C: projections + scatter ----------------
__global__ __launch_bounds__(256)
void k_proj(const unsigned short* __restrict__ h_rna,
            const unsigned short* __restrict__ h_atac,
            const float* __restrict__ W_rmu, const float* __restrict__ b_rmu,
            const float* __restrict__ W_rvar, const float* __restrict__ b_rvar,
            const float* __restrict__ W_amu, const float* __restrict__ b_amu,
            const float* __restrict__ W_avar, const float* __restrict__ b_avar,
            const int* __restrict__ idx_rna, const int* __restrict__ idx_atac,
            float* __restrict__ mu0, float* __restrict__ var0,
            float* __restrict__ mu1, float* __restrict__ var1,
            float* __restrict__ mflag)
{
    __shared__ __align__(16) unsigned short hsh[4][2][NH];
    const int wave = threadIdx.x >> 6, lane = threadIdx.x & 63;
    const long i = (long)blockIdx.x * 4 + wave;
    *(uint4*)&hsh[wave][0][lane * 8] = *(const uint4*)(h_rna  + i * NH + lane * 8);
    *(uint4*)&hsh[wave][1][lane * 8] = *(const uint4*)(h_atac + i * NH + lane * 8);
    __syncthreads();
    const int mod = lane >> 5, oo = lane & 31;
    const int isv = oo >> 4, o = oo & 15;
    const float *W, *bias;
    if (mod == 0) { W = isv ? W_rvar : W_rmu; bias = isv ? b_rvar : b_rmu; }
    else          { W = isv ? W_avar : W_amu; bias = isv ? b_avar : b_amu; }
    const unsigned short* hr = hsh[wave][mod];
    const float* wrow = W + o * NH;
    float a = 0.f;
#pragma unroll 4
    for (int k = 0; k < NH; k += 4) {
        float4 w = *(const float4*)(wrow + k);
        a += bf2f(hr[k]) * w.x + bf2f(hr[k+1]) * w.y + bf2f(hr[k+2]) * w.z + bf2f(hr[k+3]) * w.w;
    }
    a += bias[o];
    const int tgt = (mod == 0) ? idx_rna[i] : idx_atac[i];
    float* mu  = mod ? mu1  : mu0;
    float* var = mod ? var1 : var0;
    if (!isv) mu[(long)tgt * 16 + o] = a;
    else      var[(long)tgt * 16 + o] = expf(a);
    if (oo == 0) mflag[(long)mod * NS + tgt] = 1.f;
}

// ---------------- stage C: PoE combine + q + decoder hidden ----------------
__global__ __launch_bounds__(256)
void k_combine(const float* __restrict__ mu0, const float* __restrict__ var0,
               const float* __restrict__ mu1, const float* __restrict__ var1,
               const float* __restrict__ mflag,
               const float* __restrict__ eps, const float* __restrict__ cluster,
               const float* __restrict__ W_d1,
               const float* __restrict__ s_d, const float* __restrict__ t_d,
               float* __restrict__ o_zmu, float* __restrict__ o_zvar,
               float* __restrict__ o_z, float* __restrict__ o_q,
               unsigned short* __restrict__ h_d)
{
    __shared__ float zsh[4][16];
    const int wave = threadIdx.x >> 6, lane = threadIdx.x & 63;
    const long i = (long)blockIdx.x * 4 + wave;
    if (lane < 16) {
        const int d = lane;
        const float f0 = mflag[i], f1 = mflag[NS + i];
        float ts = 1.f, num = 0.f;
        if (f0 != 0.f) { float iv = 1.f / var0[i*16+d]; ts += iv; num += mu0[i*16+d] * iv; }
        if (f1 != 0.f) { float iv = 1.f / var1[i*16+d]; ts += iv; num += mu1[i*16+d] * iv; }
        const float zm = num / ts, zv = 1.f / ts;
        const float z = zm + zv * eps[i*16+d];
        o_zmu[i*16+d] = zm; o_zvar[i*16+d] = zv; o_z[i*16+d] = z;
        zsh[wave][d] = z;
    }
    __syncthreads();
    float zreg[16];
#pragma unroll
    for (int d = 0; d < 16; d++) zreg[d] = zsh[wave][d];
    float qk = 0.f;
    if (lane < KC) {
        float d2 = 0.f;
#pragma unroll
        for (int d = 0; d < 16; d++) { float df = zreg[d] - cluster[lane*16+d]; d2 += df*df; }
        qk = 1.f / (1.f + d2);
    }
    float ssum = qk;
#pragma unroll
    for (int off = 16; off > 0; off >>= 1) ssum += __shfl_xor(ssum, off, 32);
    if (lane < KC) o_q[i * KC + lane] = qk / ssum;
#pragma unroll
    for (int j = 0; j < 8; j++) {
        const int c = lane + 64 * j;
        float a = 0.f;
#pragma unroll
        for (int d = 0; d < 16; d += 4) {
            float4 w = *(const float4*)(W_d1 + c * 16 + d);
            a += zreg[d] * w.x + zreg[d+1] * w.y + zreg[d+2] * w.z + zreg[d+3] * w.w;
        }
        a = fmaxf(a * s_d[c] + t_d[c], 0.f);
        h_d[i * NH + c] = f2bf(a);
    }
}

// ---------------- launcher ----------------
extern "C" void kernel_launch(void* const* d_in, const int* in_sizes, int n_in,
                              void* d_out, int out_size, void* d_ws, size_t ws_size,
                              hipStream_t stream)
{
    const float* rna    = (const float*)d_in[0];
    const float* atac   = (const float*)d_in[1];
    const int*   i_rna  = (const int*)d_in[2];
    const int*   i_atac = (const int*)d_in[3];
    const float* eps    = (const float*)d_in[4];
    const float* W_r1   = (const float*)d_in[5];
    const float* b_r1   = (const float*)d_in[6];
    const float* g_r    = (const float*)d_in[7];
    const float* be_r   = (const float*)d_in[8];
    const float* m_r    = (const float*)d_in[9];
    const float* v_r    = (const float*)d_in[10];
    const float* W_rmu  = (const float*)d_in[11];
    const float* b_rmu  = (const float*)d_in[12];
    const float* W_rvar = (const float*)d_in[13];
    const float* b_rvar = (const float*)d_in[14];
    const float* W_a1   = (const float*)d_in[15];
    const float* b_a1   = (const float*)d_in[16];
    const float* g_a    = (const float*)d_in[17];
    const float* be_a   = (const float*)d_in[18];
    const float* m_a    = (const float*)d_in[19];
    const float* v_a    = (const float*)d_in[20];
    const float* W_amu  = (const float*)d_in[21];
    const float* b_amu  = (const float*)d_in[22];
    const float* W_avar = (const float*)d_in[23];
    const float* b_avar = (const float*)d_in[24];
    const float* W_d1   = (const float*)d_in[25];
    const float* b_d1   = (const float*)d_in[26];
    const float* g_d    = (const float*)d_in[27];
    const float* be_d   = (const float*)d_in[28];
    const float* m_d    = (const float*)d_in[29];
    const float* v_d    = (const float*)d_in[30];
    const float* W_d4   = (const float*)d_in[31];
    const float* b_d4   = (const float*)d_in[32];
    const float* clus   = (const float*)d_in[33];
    (void)in_sizes; (void)n_in; (void)out_size;

    char* w = (char*)d_ws;
    size_t off = 0;
    auto carve = [&](size_t bytes) { void* p = w + off; off += (bytes + 255) & ~(size_t)255; return p; };
    unsigned short* wr1b  = (unsigned short*)carve((size_t)NH * NF1c * 2);
    unsigned short* wa1b  = (unsigned short*)carve((size_t)NH * NF2c * 2);
    unsigned short* wd4b  = (unsigned short*)carve((size_t)NREC * NH * 2);
    unsigned short* hrna  = (unsigned short*)carve((size_t)NS * NH * 2);
    unsigned short* hatac = (unsigned short*)carve((size_t)NS * NH * 2);
    unsigned short* hd    = (unsigned short*)carve((size_t)NS * NH * 2);
    float* mu0   = (float*)carve((size_t)NS * 16 * 4);
    float* var0  = (float*)carve((size_t)NS * 16 * 4);
    float* mu1   = (float*)carve((size_t)NS * 16 * 4);
    float* var1  = (float*)carve((size_t)NS * 16 * 4);
    float* mflag = (float*)carve((size_t)2 * NS * 4);
    float* st    = (float*)carve((size_t)6 * NH * 4);
    if (off > ws_size) return;  // insufficient workspace -> loud validation failure

    float* s_r = st;          float* t_r = st + NH;
    float* s_a = st + 2*NH;   float* t_a = st + 3*NH;
    float* s_d = st + 4*NH;   float* t_d = st + 5*NH;

    float* out    = (float*)d_out;
    float* o_rec  = out;
    float* o_zmu  = out + (size_t)NS * NREC;
    float* o_zvar = o_zmu + (size_t)NS * 16;
    float* o_z    = o_zvar + (size_t)NS * 16;
    float* o_q    = o_z + (size_t)NS * 16;

    // prep
    k_cvt<<<1024, 256, 0, stream>>>(W_r1, wr1b, NH * NF1c / 4);
    k_cvt<<<2048, 256, 0, stream>>>(W_a1, wa1b, NH * NF2c / 4);
    k_cvt<<<2048, 256, 0, stream>>>(W_d4, wd4b, NREC * NH / 4);
    k_prep_st<<<2, 256, 0, stream>>>(g_r, be_r, m_r, v_r, b_r1, s_r, t_r, NH);
    k_prep_st<<<2, 256, 0, stream>>>(g_a, be_a, m_a, v_a, b_a1, s_a, t_a, NH);
    k_prep_st<<<2, 256, 0, stream>>>(g_d, be_d, m_d, v_d, b_d1, s_d, t_d, NH);
    k_zero<<<(2 * NS + 255) / 256, 256, 0, stream>>>(mflag, 2 * NS);

    dim3 blk(256);
    // encoder GEMMs: BK=64, ntn=4 (N=512), ntm=128 -> 512 blocks (512 % 8 == 0)
    k_gemm<0, 0, 64><<<512, blk, 0, stream>>>(rna,  wr1b, NF1c, NH, 4, s_r, t_r, hrna,  nullptr);
    k_gemm<0, 0, 64><<<512, blk, 0, stream>>>(atac, wa1b, NF2c, NH, 4, s_a, t_a, hatac, nullptr);
    k_proj<<<NS / 4, blk, 0, stream>>>(hrna, hatac, W_rmu, b_rmu, W_rvar, b_rvar,
                                       W_amu, b_amu, W_avar, b_avar, i_rna, i_atac,
                                       mu0, var0, mu1, var1, mflag);
    k_combine<<<NS / 4, blk, 0, stream>>>(mu0, var0, mu1, var1, mflag, eps, clus,
                                          W_d1, s_d, t_d, o_zmu, o_zvar, o_z, o_q, hd);
    // recon GEMM: BK=32, ntn=94 (N=12000), ntm=128 -> 12032 blocks (12032 % 8 == 0)
    k_gemm<1, 1, 32><<<94 * 128, blk, 0, stream>>>(hd, wd4b, NH, NREC, 94, b_d4, nullptr, nullptr, o_rec);
}